// Round 3
// baseline (505.472 us; speedup 1.0000x reference)
//
#include <hip/hip_runtime.h>
#include <hip/hip_bf16.h>

typedef __attribute__((ext_vector_type(8))) _Float16 f16x8;
typedef __attribute__((ext_vector_type(4))) float    f32x4;

#define B_    16384
#define N_    32
#define DIN_  128
#define DOUT_ 256

// Pack W (DIN x DOUT, fp32) into fp16 B-fragment order for mfma_f32_16x16x32_f16.
// Fragment: lane l holds B[k = ks*32 + (l>>4)*8 + j][o = ot*16 + (l&15)], j=0..7.
// Flat: wp[(((ks*16)+ot)*64 + l)*8 + j].  4*16*64*8 = 32768 f16 = 64KB.
__global__ void prep_w(const float* __restrict__ W, _Float16* __restrict__ wp) {
    int tid = blockIdx.x * 256 + threadIdx.x;   // 0..4095
    int ks = tid >> 10;
    int ot = (tid >> 6) & 15;
    int l  = tid & 63;
    int k0 = ks * 32 + ((l >> 4) << 3);
    int o  = ot * 16 + (l & 15);
    _Float16 v[8];
#pragma unroll
    for (int j = 0; j < 8; ++j) v[j] = (_Float16)W[(size_t)(k0 + j) * DOUT_ + o];
    *reinterpret_cast<f16x8*>(&wp[(size_t)tid * 8]) = *reinterpret_cast<f16x8*>(v);
}

// One wave per batch element. NO shared memory anywhere — all cross-lane data
// movement is shuffles. Lane decomposition: col = l&15, q = l>>4.
// acc[mt][ot][r] = x[n][o], n = mt*16 + q*4 + r, o = ot*16 + col.
__global__ __launch_bounds__(256, 1) void dyr_main(
    const float* __restrict__ embeds, const float* __restrict__ weights,
    const _Float16* __restrict__ wp,  const float* __restrict__ bias,
    float* __restrict__ out)
{
    const int tid = threadIdx.x;
    const int wv  = tid >> 6;
    const int l   = tid & 63;
    const int col = l & 15;
    const int q   = l >> 4;
    const size_t b = (size_t)blockIdx.x * 4 + wv;

    const float* eb = embeds + b * (size_t)(N_ * DIN_);

    f32x4 acc[2][16];
#pragma unroll
    for (int mt = 0; mt < 2; ++mt)
#pragma unroll
        for (int ot = 0; ot < 16; ++ot) acc[mt][ot] = (f32x4){0.f, 0.f, 0.f, 0.f};

    float bn = weights[b * N_ + (l & 31)];   // routing logit for n = l&31 (dup over bit 5)

    // ---- GEMM: direct global->reg A fragments (fp32->fp16), wp B fragments (L2-hot) ----
#pragma unroll
    for (int ks = 0; ks < 4; ++ks) {
        f16x8 a[2];
#pragma unroll
        for (int mt = 0; mt < 2; ++mt) {
            const float4* p4 = reinterpret_cast<const float4*>(
                eb + (size_t)(mt * 16 + col) * DIN_ + ks * 32 + q * 8);
            float4 r0 = p4[0];
            float4 r1 = p4[1];
            _Float16 av[8] = { (_Float16)r0.x, (_Float16)r0.y, (_Float16)r0.z, (_Float16)r0.w,
                               (_Float16)r1.x, (_Float16)r1.y, (_Float16)r1.z, (_Float16)r1.w };
            a[mt] = *reinterpret_cast<f16x8*>(av);
        }
#pragma unroll
        for (int ot = 0; ot < 16; ++ot) {
            f16x8 bf = *reinterpret_cast<const f16x8*>(
                &wp[((size_t)(ks * 16 + ot) * 64 + l) * 8]);
            acc[0][ot] = __builtin_amdgcn_mfma_f32_16x16x32_f16(a[0], bf, acc[0][ot], 0, 0, 0);
            acc[1][ot] = __builtin_amdgcn_mfma_f32_16x16x32_f16(a[1], bf, acc[1][ot], 0, 0, 0);
        }
    }

    // ---- bias ----
#pragma unroll
    for (int ot = 0; ot < 16; ++ot) {
        float bv = bias[ot * 16 + col];
#pragma unroll
        for (int mt = 0; mt < 2; ++mt)
#pragma unroll
            for (int r = 0; r < 4; ++r) acc[mt][ot][r] += bv;
    }

    // ---- row norms + normalize (u_hat stays in acc) ----
#pragma unroll
    for (int mt = 0; mt < 2; ++mt)
#pragma unroll
        for (int r = 0; r < 4; ++r) {
            float p = 0.f;
#pragma unroll
            for (int ot = 0; ot < 16; ++ot) p += acc[mt][ot][r] * acc[mt][ot][r];
            p += __shfl_xor(p, 1); p += __shfl_xor(p, 2);
            p += __shfl_xor(p, 4); p += __shfl_xor(p, 8);
            float rn = 1.0f / fmaxf(sqrtf(p), 1e-12f);
#pragma unroll
            for (int ot = 0; ot < 16; ++ot) acc[mt][ot][r] *= rn;
        }

    // ---- dynamic routing: pure shuffles ----
    float cme = 0.f;
    float vv[16];
#pragma unroll
    for (int it = 0; it < 3; ++it) {
        // softmax over n=0..31 (lanes duplicated over bit 5)
        float mx = bn;
        mx = fmaxf(mx, __shfl_xor(mx, 1));  mx = fmaxf(mx, __shfl_xor(mx, 2));
        mx = fmaxf(mx, __shfl_xor(mx, 4));  mx = fmaxf(mx, __shfl_xor(mx, 8));
        mx = fmaxf(mx, __shfl_xor(mx, 16));
        float ex = __expf(bn - mx);
        float sm = ex;
        sm += __shfl_xor(sm, 1); sm += __shfl_xor(sm, 2); sm += __shfl_xor(sm, 4);
        sm += __shfl_xor(sm, 8); sm += __shfl_xor(sm, 16);
        cme = ex * (32.0f / sm);

        float cv[2][4];
#pragma unroll
        for (int mt = 0; mt < 2; ++mt)
#pragma unroll
            for (int r = 0; r < 4; ++r) cv[mt][r] = __shfl(cme, mt * 16 + q * 4 + r);

        // s[o] = sum_n c[n]*u[n][o]; reduce across q-groups (lane bits 4,5)
        float sv[16];
#pragma unroll
        for (int ot = 0; ot < 16; ++ot) {
            float s = 0.f;
#pragma unroll
            for (int mt = 0; mt < 2; ++mt)
#pragma unroll
                for (int r = 0; r < 4; ++r) s += cv[mt][r] * acc[mt][ot][r];
            s += __shfl_xor(s, 16); s += __shfl_xor(s, 32);
            sv[ot] = s;
        }

        // sq = ||s||^2 : sum over ot in-reg, over col via bits 0..3
        float sq = 0.f;
#pragma unroll
        for (int ot = 0; ot < 16; ++ot) sq += sv[ot] * sv[ot];
        sq += __shfl_xor(sq, 1); sq += __shfl_xor(sq, 2);
        sq += __shfl_xor(sq, 4); sq += __shfl_xor(sq, 8);
        float scale = sq / ((1.0f + sq) * sqrtf(sq + 1e-9f));
#pragma unroll
        for (int ot = 0; ot < 16; ++ot) vv[ot] = scale * sv[ot];

        if (it < 2) {
            // agree[n] = sum_o u[n][o]*v[o]; butterfly over cols -> uniform per q-group
            float ag[2][4];
#pragma unroll
            for (int mt = 0; mt < 2; ++mt)
#pragma unroll
                for (int r = 0; r < 4; ++r) {
                    float ap = 0.f;
#pragma unroll
                    for (int ot = 0; ot < 16; ++ot) ap += acc[mt][ot][r] * vv[ot];
                    ap += __shfl_xor(ap, 1); ap += __shfl_xor(ap, 2);
                    ap += __shfl_xor(ap, 4); ap += __shfl_xor(ap, 8);
                    ag[mt][r] = ap;
                }
            // transpose agree[n] -> lane n, register-only:
            // lane l wants agree[n=l&31]; it lives in q-group (l>>2)&3 as
            // ag[(l>>4)&1][l&3]. Fetch all 8 from lane ((l>>2)&3)*16, select statically.
            {
                int srcl = ((l >> 2) & 3) << 4;
                float t0[4], t1[4];
#pragma unroll
                for (int r = 0; r < 4; ++r) {
                    t0[r] = __shfl(ag[0][r], srcl);
                    t1[r] = __shfl(ag[1][r], srcl);
                }
                float tm[4];
#pragma unroll
                for (int r = 0; r < 4; ++r) tm[r] = ((l >> 4) & 1) ? t1[r] : t0[r];
                float g0 = (l & 1) ? tm[1] : tm[0];
                float g1 = (l & 1) ? tm[3] : tm[2];
                bn += (l & 2) ? g1 : g0;
            }
        }
    }

    // ---- outputs: poses (B x 256) then c_out (B x 32), flat-concatenated ----
#pragma unroll
    for (int j = 0; j < 4; ++j) {
        // val = vv[q*4 + j], selected without dynamic register indexing
        float v0 = (q & 1) ? vv[4 + j]  : vv[j];
        float v1 = (q & 1) ? vv[12 + j] : vv[8 + j];
        float val = (q & 2) ? v1 : v0;
        out[b * DOUT_ + (size_t)(q * 4 + j) * 16 + col] = val;
    }
    if (l < 32)
        out[(size_t)B_ * DOUT_ + b * N_ + l] = cme;
}

extern "C" void kernel_launch(void* const* d_in, const int* in_sizes, int n_in,
                              void* d_out, int out_size, void* d_ws, size_t ws_size,
                              hipStream_t stream) {
    const float* embeds  = (const float*)d_in[0];
    const float* weights = (const float*)d_in[1];
    const float* W       = (const float*)d_in[2];
    const float* bias    = (const float*)d_in[3];
    float* out = (float*)d_out;
    _Float16* wp = (_Float16*)d_ws;    // 64 KB packed fp16 W

    prep_w<<<16, 256, 0, stream>>>(W, wp);
    dyr_main<<<B_ / 4, 256, 0, stream>>>(embeds, weights, wp, bias, out);
}

// Round 4
// 457.177 us; speedup vs baseline: 1.1056x; 1.1056x over previous
//
#include <hip/hip_runtime.h>
#include <hip/hip_bf16.h>

typedef __attribute__((ext_vector_type(8))) _Float16 f16x8;
typedef __attribute__((ext_vector_type(4))) _Float16 f16x4;
typedef __attribute__((ext_vector_type(4))) float    f32x4;

#define B_    16384
#define N_    32
#define DIN_  128
#define DOUT_ 256

// Pack W (DIN x DOUT, fp32) into fp16 B-fragment order for mfma_f32_16x16x32_f16.
// Fragment: lane l holds B[k = ks*32 + (l>>4)*8 + j][o = ot*16 + (l&15)], j=0..7.
// Flat: wp[(((ks*16)+ot)*64 + l)*8 + j].  4*16*64*8 = 32768 f16 = 64KB.
__global__ void prep_w(const float* __restrict__ W, _Float16* __restrict__ wp) {
    int tid = blockIdx.x * 256 + threadIdx.x;   // 0..4095
    int ks = tid >> 10;
    int ot = (tid >> 6) & 15;
    int l  = tid & 63;
    int k0 = ks * 32 + ((l >> 4) << 3);
    int o  = ot * 16 + (l & 15);
    _Float16 v[8];
#pragma unroll
    for (int j = 0; j < 8; ++j) v[j] = (_Float16)W[(size_t)(k0 + j) * DOUT_ + o];
    *reinterpret_cast<f16x8*>(&wp[(size_t)tid * 8]) = *reinterpret_cast<f16x8*>(v);
}

// Block = 4 batch elements, one per wave. Each wave stages ITS OWN embeds tile
// (coalesced float4) into a private LDS region, then runs GEMM + routing fully
// intra-wave (shuffles only). Single __syncthreads pins LDS store->load order.
// Lane decomposition: col = l&15, q = l>>4.
// acc[mt][ot][r] = x[n][o], n = mt*16 + q*4 + r, o = ot*16 + col.
__global__ __launch_bounds__(256, 2) void dyr_main(
    const float* __restrict__ embeds, const float* __restrict__ weights,
    const _Float16* __restrict__ wp,  const float* __restrict__ bias,
    float* __restrict__ out)
{
    __shared__ _Float16 elds[4][32 * 136];   // 4 x 8704 B = 34816 B (stride 136 -> 16B-aligned rows)

    const int tid = threadIdx.x;
    const int wv  = tid >> 6;
    const int l   = tid & 63;
    const int col = l & 15;
    const int q   = l >> 4;
    const size_t b = (size_t)blockIdx.x * 4 + wv;

    // ---- stage this wave's embeds tile (32x128 fp32 = 1024 float4), coalesced ----
    const float4* e4 = reinterpret_cast<const float4*>(embeds + b * (size_t)(N_ * DIN_));
#pragma unroll
    for (int j = 0; j < 16; ++j) {
        int fi = j * 64 + l;              // consecutive lanes -> consecutive float4
        float4 v = e4[fi];
        int m = fi >> 5;                  // row (32 float4 per row)
        int k = (fi & 31) << 2;           // col
        _Float16 pk[4] = { (_Float16)v.x, (_Float16)v.y, (_Float16)v.z, (_Float16)v.w };
        *reinterpret_cast<f16x4*>(&elds[wv][m * 136 + k]) = *reinterpret_cast<f16x4*>(pk);
    }
    float bn = weights[b * N_ + (l & 31)];   // routing logit for n = l&31 (dup over bit 5)
    __syncthreads();                         // pin LDS write -> read order

    // ---- GEMM: A frags from LDS (ds_read_b128), B frags from wp (L2-hot) ----
    f32x4 acc[2][16];
#pragma unroll
    for (int mt = 0; mt < 2; ++mt)
#pragma unroll
        for (int ot = 0; ot < 16; ++ot) acc[mt][ot] = (f32x4){0.f, 0.f, 0.f, 0.f};

    const int aoff = col * 136 + q * 8;      // A-frag: m=col(+16mt), k=q*8(+32ks)
#pragma unroll
    for (int ks = 0; ks < 4; ++ks) {
        f16x8 a0 = *reinterpret_cast<const f16x8*>(&elds[wv][aoff + ks * 32]);
        f16x8 a1 = *reinterpret_cast<const f16x8*>(&elds[wv][aoff + 16 * 136 + ks * 32]);
#pragma unroll
        for (int ot = 0; ot < 16; ++ot) {
            f16x8 bf = *reinterpret_cast<const f16x8*>(
                &wp[((size_t)(ks * 16 + ot) * 64 + l) * 8]);
            acc[0][ot] = __builtin_amdgcn_mfma_f32_16x16x32_f16(a0, bf, acc[0][ot], 0, 0, 0);
            acc[1][ot] = __builtin_amdgcn_mfma_f32_16x16x32_f16(a1, bf, acc[1][ot], 0, 0, 0);
        }
    }

    // ---- bias ----
#pragma unroll
    for (int ot = 0; ot < 16; ++ot) {
        float bv = bias[ot * 16 + col];
#pragma unroll
        for (int mt = 0; mt < 2; ++mt)
#pragma unroll
            for (int r = 0; r < 4; ++r) acc[mt][ot][r] += bv;
    }

    // ---- row norms + normalize (u_hat stays in acc) ----
#pragma unroll
    for (int mt = 0; mt < 2; ++mt)
#pragma unroll
        for (int r = 0; r < 4; ++r) {
            float p = 0.f;
#pragma unroll
            for (int ot = 0; ot < 16; ++ot) p += acc[mt][ot][r] * acc[mt][ot][r];
            p += __shfl_xor(p, 1); p += __shfl_xor(p, 2);
            p += __shfl_xor(p, 4); p += __shfl_xor(p, 8);
            float rn = 1.0f / fmaxf(sqrtf(p), 1e-12f);
#pragma unroll
            for (int ot = 0; ot < 16; ++ot) acc[mt][ot][r] *= rn;
        }

    // ---- dynamic routing: pure shuffles, fully intra-wave ----
    float cme = 0.f;
    float vv[16];
#pragma unroll
    for (int it = 0; it < 3; ++it) {
        // softmax over n=0..31 (lanes duplicated over bit 5)
        float mx = bn;
        mx = fmaxf(mx, __shfl_xor(mx, 1));  mx = fmaxf(mx, __shfl_xor(mx, 2));
        mx = fmaxf(mx, __shfl_xor(mx, 4));  mx = fmaxf(mx, __shfl_xor(mx, 8));
        mx = fmaxf(mx, __shfl_xor(mx, 16));
        float ex = __expf(bn - mx);
        float sm = ex;
        sm += __shfl_xor(sm, 1); sm += __shfl_xor(sm, 2); sm += __shfl_xor(sm, 4);
        sm += __shfl_xor(sm, 8); sm += __shfl_xor(sm, 16);
        cme = ex * (32.0f / sm);

        float cv[2][4];
#pragma unroll
        for (int mt = 0; mt < 2; ++mt)
#pragma unroll
            for (int r = 0; r < 4; ++r) cv[mt][r] = __shfl(cme, mt * 16 + q * 4 + r);

        // s[o] = sum_n c[n]*u[n][o]; reduce across q-groups (lane bits 4,5)
        float sv[16];
#pragma unroll
        for (int ot = 0; ot < 16; ++ot) {
            float s = 0.f;
#pragma unroll
            for (int mt = 0; mt < 2; ++mt)
#pragma unroll
                for (int r = 0; r < 4; ++r) s += cv[mt][r] * acc[mt][ot][r];
            s += __shfl_xor(s, 16); s += __shfl_xor(s, 32);
            sv[ot] = s;
        }

        // sq = ||s||^2 : sum over ot in-reg, over col via bits 0..3
        float sq = 0.f;
#pragma unroll
        for (int ot = 0; ot < 16; ++ot) sq += sv[ot] * sv[ot];
        sq += __shfl_xor(sq, 1); sq += __shfl_xor(sq, 2);
        sq += __shfl_xor(sq, 4); sq += __shfl_xor(sq, 8);
        float scale = sq / ((1.0f + sq) * sqrtf(sq + 1e-9f));
#pragma unroll
        for (int ot = 0; ot < 16; ++ot) vv[ot] = scale * sv[ot];

        if (it < 2) {
            // agree[n] = sum_o u[n][o]*v[o]; butterfly over cols -> uniform per q-group
            float ag[2][4];
#pragma unroll
            for (int mt = 0; mt < 2; ++mt)
#pragma unroll
                for (int r = 0; r < 4; ++r) {
                    float ap = 0.f;
#pragma unroll
                    for (int ot = 0; ot < 16; ++ot) ap += acc[mt][ot][r] * vv[ot];
                    ap += __shfl_xor(ap, 1); ap += __shfl_xor(ap, 2);
                    ap += __shfl_xor(ap, 4); ap += __shfl_xor(ap, 8);
                    ag[mt][r] = ap;
                }
            // register-only transpose agree[n] -> lane n:
            // lane l wants agree[n=l&31], held by q-group (l>>2)&3 as ag[(l>>4)&1][l&3].
            {
                int srcl = ((l >> 2) & 3) << 4;
                float t0[4], t1[4];
#pragma unroll
                for (int r = 0; r < 4; ++r) {
                    t0[r] = __shfl(ag[0][r], srcl);
                    t1[r] = __shfl(ag[1][r], srcl);
                }
                float tm[4];
#pragma unroll
                for (int r = 0; r < 4; ++r) tm[r] = ((l >> 4) & 1) ? t1[r] : t0[r];
                float g0 = (l & 1) ? tm[1] : tm[0];
                float g1 = (l & 1) ? tm[3] : tm[2];
                bn += (l & 2) ? g1 : g0;
            }
        }
    }

    // ---- outputs: poses (B x 256) then c_out (B x 32), flat-concatenated ----
#pragma unroll
    for (int j = 0; j < 4; ++j) {
        // val = vv[q*4 + j], selected without dynamic register indexing
        float v0 = (q & 1) ? vv[4 + j]  : vv[j];
        float v1 = (q & 1) ? vv[12 + j] : vv[8 + j];
        float val = (q & 2) ? v1 : v0;
        out[b * DOUT_ + (size_t)(q * 4 + j) * 16 + col] = val;
    }
    if (l < 32)
        out[(size_t)B_ * DOUT_ + b * N_ + l] = cme;
}

extern "C" void kernel_launch(void* const* d_in, const int* in_sizes, int n_in,
                              void* d_out, int out_size, void* d_ws, size_t ws_size,
                              hipStream_t stream) {
    const float* embeds  = (const float*)d_in[0];
    const float* weights = (const float*)d_in[1];
    const float* W       = (const float*)d_in[2];
    const float* bias    = (const float*)d_in[3];
    float* out = (float*)d_out;
    _Float16* wp = (_Float16*)d_ws;    // 64 KB packed fp16 W

    prep_w<<<16, 256, 0, stream>>>(W, wp);
    dyr_main<<<B_ / 4, 256, 0, stream>>>(embeds, weights, wp, bias, out);
}